// Round 5
// baseline (52813.776 us; speedup 1.0000x reference)
//
#include <hip/hip_runtime.h>
#include <cmath>

#define SEQ 4096
#define INP 457
#define EMB 2048
#define NWG_E 256   // encoder: 1 WG (512 thr) per CU; 160 weight floats/thread pinned in VGPRs
#define NWG_D 16    // decoder: 16 WGs x 32 c-indices = 512 >= 457

typedef unsigned long long u64t;
typedef float f32x4 __attribute__((ext_vector_type(4)));
typedef float f32x2 __attribute__((ext_vector_type(2)));
typedef unsigned u32x4 __attribute__((ext_vector_type(4)));

__device__ __forceinline__ float sigf(float v) { return 1.0f / (1.0f + expf(-v)); }

// Opaque pin: value becomes output of an opaque asm -> compiler cannot rematerialize
// the original load; the value must stay live in a VGPR.
#define PIN(v) asm volatile("" : "+v"(v))

#define QNAN __builtin_bit_cast(float, 0x7fc00000u)

// MALL-coherent loads (system scope, bypass L1+L2). Manual vmcnt(0) because the compiler
// cannot see these are loads. Hidden asm vmem only makes compiler waitcnts over-wait -> safe.
__device__ __forceinline__ f32x4 mall16(const f32x4* p) {
  f32x4 v;
  asm volatile("global_load_dwordx4 %0, %1, off sc0 sc1\n\ts_waitcnt vmcnt(0)"
               : "=v"(v) : "v"(p) : "memory");
  return v;
}
__device__ __forceinline__ u32x4 mall16u(const u32x4* p) {
  u32x4 v;
  asm volatile("global_load_dwordx4 %0, %1, off sc0 sc1\n\ts_waitcnt vmcnt(0)"
               : "=v"(v) : "v"(p) : "memory");
  return v;
}
__device__ __forceinline__ f32x2 mall8(const f32x2* p) {
  f32x2 v;
  asm volatile("global_load_dwordx2 %0, %1, off sc0 sc1\n\ts_waitcnt vmcnt(0)"
               : "=v"(v) : "v"(p) : "memory");
  return v;
}

// ---------------- bias precompute ----------------
__global__ void bias_kernel(const float* __restrict__ ebih, const float* __restrict__ ebhh,
                            const float* __restrict__ dbih, const float* __restrict__ dbhh,
                            float* __restrict__ bsum, float* __restrict__ btot) {
  int i = blockIdx.x * 256 + threadIdx.x;
  if (i < 4 * EMB) bsum[i] = ebih[i] + ebhh[i];
  if (i < 4 * INP) btot[i] = dbih[i] + dbhh[i];
}

// ---------------- Wfold = (dec_Wih + dec_Whh) @ dec_Whr  (1828 x 480, pad cols zero) ----------------
__global__ __launch_bounds__(256) void fold_gemm(const float* __restrict__ dWih,
                                                 const float* __restrict__ dWhh,
                                                 const float* __restrict__ dWhr,
                                                 float* __restrict__ C) {
  const int bx = blockIdx.x, by = blockIdx.y;
  const int tid = threadIdx.x;
  const int tx = tid & 15, ty = tid >> 4;
  __shared__ float As[16][65];
  __shared__ float Bs[16][65];
  float acc[4][4] = {};
  for (int k0 = 0; k0 < EMB; k0 += 16) {
#pragma unroll
    for (int e = 0; e < 4; ++e) {
      int eid = tid * 4 + e;
      int m = eid >> 4, k = eid & 15;
      int row = by * 64 + m;
      float v = 0.0f;
      if (row < 4 * INP) {
        size_t a = (size_t)row * EMB + k0 + k;
        v = dWih[a] + dWhh[a];
      }
      As[k][m] = v;
    }
#pragma unroll
    for (int e = 0; e < 4; ++e) {
      int eid = tid * 4 + e;
      int k = eid >> 6, c = eid & 63;
      int col = bx * 64 + c;
      Bs[k][c] = (col < INP) ? dWhr[(size_t)(k0 + k) * INP + col] : 0.0f;
    }
    __syncthreads();
#pragma unroll
    for (int k = 0; k < 16; ++k) {
      float a0 = As[k][ty * 4 + 0], a1 = As[k][ty * 4 + 1], a2 = As[k][ty * 4 + 2], a3 = As[k][ty * 4 + 3];
      float b0 = Bs[k][tx * 4 + 0], b1 = Bs[k][tx * 4 + 1], b2 = Bs[k][tx * 4 + 2], b3 = Bs[k][tx * 4 + 3];
      acc[0][0] += a0 * b0; acc[0][1] += a0 * b1; acc[0][2] += a0 * b2; acc[0][3] += a0 * b3;
      acc[1][0] += a1 * b0; acc[1][1] += a1 * b1; acc[1][2] += a1 * b2; acc[1][3] += a1 * b3;
      acc[2][0] += a2 * b0; acc[2][1] += a2 * b1; acc[2][2] += a2 * b2; acc[2][3] += a2 * b3;
      acc[3][0] += a3 * b0; acc[3][1] += a3 * b1; acc[3][2] += a3 * b2; acc[3][3] += a3 * b3;
    }
    __syncthreads();
  }
#pragma unroll
  for (int i = 0; i < 4; ++i) {
    int row = by * 64 + ty * 4 + i;
    if (row >= 4 * INP) continue;
#pragma unroll
    for (int j = 0; j < 4; ++j) {
      int col = bx * 64 + tx * 4 + j;
      if (col < 480) C[(size_t)row * 480 + col] = acc[i][j];
    }
  }
}

// ---------------- persistent encoder: counter-flag + depth-2 data ring ----------------
// 256 WGs x 512 thr. WG w owns h-indices [w*8, w*8+8). Weights pinned in VGPRs (160 f/thread).
// NEW vs R3 (which poll-spun on the 2MB data itself = ~7 TB/s of MALL poll traffic,
// congesting the fabric that sets the poll latency):
//  * Producers publish h(t+1) -> vmcnt(0) store-ack -> ONE fetch_add to cnt[wg&3]
//    (4 counters x 64 WGs each; monotone, never reset).
//  * Consumers: lane 0 of each wave polls the 16B counter line until all 4 counters
//    >= 64*t (poll traffic ~0.1 TB/s, ~4000x less), then EVERY lane does one bulk 16B
//    MALL read of its granule. Counter-visible => producer stores were acked at the
//    coherence point => bulk read sees them.
//  * Monotone >= comparison: no NaN sentinel, no re-arm, no ABA -> no deadlock modes.
//  * Depth-2 ring: at step t, read slot t&1, publish into slot (t+1)&1 (overwrites
//    h(t-1)). Safe: reaching phase-publish requires cnt >= 64t, i.e. every WG completed
//    step t-1 INCLUDING its bulk read of h(t-1). h_enc = h_4096 lands in slot 0.
__global__ __launch_bounds__(512) __attribute__((amdgpu_waves_per_eu(2, 2))) void enc_kernel(
    const float* __restrict__ x, const float* __restrict__ Wih,
    const float* __restrict__ Whh, const float* __restrict__ bsum,
    float* __restrict__ hbuf, unsigned* __restrict__ cnt) {
  const int tid = threadIdx.x;
  const int wg  = blockIdx.x;
  const int j   = tid & 7;
  const int kc  = tid >> 3;            // 0..63 (wave-local: wave w has kc in [8w, 8w+8))
  const int jbase = wg * 8;

  float wh[4][32];
  float wi[4][8];
#pragma unroll
  for (int g = 0; g < 4; ++g) {
    const size_t row = (size_t)(g * EMB + jbase + j);
    const float* wp = Whh + row * EMB + kc * 32;
#pragma unroll
    for (int q = 0; q < 8; ++q) {
      const float4 v = *(const float4*)(wp + 4 * q);
      wh[g][q * 4 + 0] = v.x; wh[g][q * 4 + 1] = v.y;
      wh[g][q * 4 + 2] = v.z; wh[g][q * 4 + 3] = v.w;
    }
    const float* ip = Wih + row * INP;
#pragma unroll
    for (int i = 0; i < 8; ++i) {
      const int c = kc * 8 + i;
      wi[g][i] = (c < INP) ? ip[c] : 0.0f;
    }
  }
  // pin all 160 weight floats in VGPRs
#pragma unroll
  for (int g = 0; g < 4; ++g) {
#pragma unroll
    for (int q = 0; q < 32; ++q) PIN(wh[g][q]);
#pragma unroll
    for (int q = 0; q < 8; ++q) PIN(wi[g][q]);
  }

  __shared__ float4 hl4[512];          // 8 KB: h_t, swizzled 16B granules, wave-local regions
  __shared__ float4 xl4[128];          // 2 KB: x_t (512 floats, pad 0), wave-local regions
  __shared__ float  partbuf[256];      // 8 waves x 8 j x 4 gates
  __shared__ float  b_s[32];
  __shared__ float  c_s[8];
  if (tid < 32) b_s[tid] = bsum[(tid >> 3) * EMB + jbase + (tid & 7)];
  if (tid < 8)  c_s[tid] = 0.0f;
  const int sw = kc & 7;
  const int hphys = tid ^ ((tid >> 3) & 7);   // write-side granule swizzle (stays in wave region)
  const int xi = (tid < INP) ? tid : 0;

  for (int t = 0; t < SEQ; ++t) {
    // ---- x load (cached, issued before wait; its latency hides under the counter poll) ----
    const float xraw = x[(size_t)t * INP + xi];

    // ---- wave leader polls the 16B counter line: all 4 counters >= 64*t ----
    if (t > 0 && (tid & 63) == 0) {
      const unsigned tgt = (unsigned)t * 64u;
      for (;;) {
        const u32x4 c = mall16u((const u32x4*)cnt);
        if (c.x >= tgt && c.y >= tgt && c.z >= tgt && c.w >= tgt) break;
      }
    }
    // reconverge; all h(t) granules are at the coherence point now
    const f32x4 g4 = mall16((const f32x4*)(hbuf + (size_t)(t & 1) * EMB) + tid);
    hl4[hphys] = make_float4(g4.x, g4.y, g4.z, g4.w);
    ((float*)xl4)[tid] = (tid < INP) ? xraw : 0.0f;
    // no barrier: same-wave DS ordering suffices (wave reads only its own region)

    // ---- MAC: 4 gates x (8 x + 32 h) ----
    float4 a0 = make_float4(0, 0, 0, 0), a1 = a0, a2 = a0, a3 = a0;
#pragma unroll
    for (int q = 0; q < 2; ++q) {
      const float4 xq = xl4[kc * 2 + q];
      a0.x += wi[0][q * 4 + 0] * xq.x; a0.y += wi[0][q * 4 + 1] * xq.y; a0.z += wi[0][q * 4 + 2] * xq.z; a0.w += wi[0][q * 4 + 3] * xq.w;
      a1.x += wi[1][q * 4 + 0] * xq.x; a1.y += wi[1][q * 4 + 1] * xq.y; a1.z += wi[1][q * 4 + 2] * xq.z; a1.w += wi[1][q * 4 + 3] * xq.w;
      a2.x += wi[2][q * 4 + 0] * xq.x; a2.y += wi[2][q * 4 + 1] * xq.y; a2.z += wi[2][q * 4 + 2] * xq.z; a2.w += wi[2][q * 4 + 3] * xq.w;
      a3.x += wi[3][q * 4 + 0] * xq.x; a3.y += wi[3][q * 4 + 1] * xq.y; a3.z += wi[3][q * 4 + 2] * xq.z; a3.w += wi[3][q * 4 + 3] * xq.w;
    }
#pragma unroll
    for (int q = 0; q < 8; ++q) {
      const float4 hv = hl4[kc * 8 + (q ^ sw)];   // holds LOGICAL granule kc*8+q
      const int b = q * 4;
      a0.x += wh[0][b + 0] * hv.x; a0.y += wh[0][b + 1] * hv.y; a0.z += wh[0][b + 2] * hv.z; a0.w += wh[0][b + 3] * hv.w;
      a1.x += wh[1][b + 0] * hv.x; a1.y += wh[1][b + 1] * hv.y; a1.z += wh[1][b + 2] * hv.z; a1.w += wh[1][b + 3] * hv.w;
      a2.x += wh[2][b + 0] * hv.x; a2.y += wh[2][b + 1] * hv.y; a2.z += wh[2][b + 2] * hv.z; a2.w += wh[2][b + 3] * hv.w;
      a3.x += wh[3][b + 0] * hv.x; a3.y += wh[3][b + 1] * hv.y; a3.z += wh[3][b + 2] * hv.z; a3.w += wh[3][b + 3] * hv.w;
    }

    // ---- reduce 8 kc-chunks inside each wave (lane bits 3,4,5), partials to LDS ----
    float r0 = (a0.x + a0.y) + (a0.z + a0.w);
    float r1 = (a1.x + a1.y) + (a1.z + a1.w);
    float r2 = (a2.x + a2.y) + (a2.z + a2.w);
    float r3 = (a3.x + a3.y) + (a3.z + a3.w);
#pragma unroll
    for (int m = 8; m < 64; m <<= 1) {
      r0 += __shfl_xor(r0, m); r1 += __shfl_xor(r1, m);
      r2 += __shfl_xor(r2, m); r3 += __shfl_xor(r3, m);
    }
    if ((tid & 63) < 8)
      *(float4*)(partbuf + (tid >> 6) * 32 + j * 4) = make_float4(r0, r1, r2, r3);
    __syncthreads();   // the ONLY per-step barrier

    // ---- wave0: gather, activate, publish, store-ack, count ----
    if (tid < 8) {
      float s0 = 0.f, s1 = 0.f, s2 = 0.f, s3 = 0.f;
#pragma unroll
      for (int w = 0; w < 8; ++w) {
        const float4 pv = *(const float4*)(partbuf + w * 32 + tid * 4);
        s0 += pv.x; s1 += pv.y; s2 += pv.z; s3 += pv.w;
      }
      const float gi = s0 + b_s[tid], gf = s1 + b_s[8 + tid];
      const float gg = s2 + b_s[16 + tid], go = s3 + b_s[24 + tid];
      const float cN = sigf(gf) * c_s[tid] + sigf(gi) * tanhf(gg);
      c_s[tid] = cN;
      const float hN = sigf(go) * tanhf(cN);
      __hip_atomic_store(hbuf + (size_t)((t + 1) & 1) * EMB + jbase + tid, hN,
                         __ATOMIC_RELAXED, __HIP_MEMORY_SCOPE_AGENT);
      // store-ack at the coherence point, THEN advertise via the counter
      asm volatile("s_waitcnt vmcnt(0)" ::: "memory");
      if (tid == 0)
        __hip_atomic_fetch_add(cnt + (wg & 3), 1u, __ATOMIC_RELAXED, __HIP_MEMORY_SCOPE_AGENT);
    }
  }
}

// ---------------- persistent decoder (exact R3-proven version) ----------------
// 16 WGs x 512 thr. WG w owns c-indices [w*32, w*32+32). Wfold 4x30 = 120 floats/thread pinned.
// Data-is-the-flag on a depth-4 hraw ring (NaN = empty), MALL-scope (sc0 sc1) polls.
// Wave v's MAC reads dl2 granules [30v, 30v+30); lanes l<30 poll+stage those, lanes >=30 poll
// a duplicate granule folded into [0,30) of the SAME wave region. Pad lanes 457..479 are
// stored 0.0f every step so all polled granules terminate.
__global__ __launch_bounds__(512) __attribute__((amdgpu_waves_per_eu(2, 2))) void dec_kernel(
    const float* __restrict__ dWih, const float* __restrict__ Wfold,
    const float* __restrict__ btot, const float* __restrict__ henc,
    float* __restrict__ hraw, float* __restrict__ out) {
  const int tid = threadIdx.x;
  const int wg  = blockIdx.x;
  const int j   = tid & 31;
  const int kc  = tid >> 5;          // 0..15 (wave-local: wave v has kc in {2v, 2v+1})
  const int idx = wg * 32 + j;
  const bool valid = (idx < INP);
  const int id0 = valid ? idx : 0;
  const int l   = tid & 63;
  const int wv  = tid >> 6;
  int gl = l;                         // fold lane into [0,30): l, l-30, l-60
  if (gl >= 30) gl -= 30;
  if (gl >= 30) gl -= 30;
  const int gidx = 30 * wv + gl;      // polled u64 granule, always in-range & wave-local

  float wd[4][30];
#pragma unroll
  for (int g = 0; g < 4; ++g) {
    const float* wp = Wfold + (size_t)(g * INP + id0) * 480 + kc * 30;
#pragma unroll
    for (int q = 0; q < 15; ++q) {
      const float2 v = valid ? *(const float2*)(wp + 2 * q) : make_float2(0.0f, 0.0f);
      wd[g][q * 2 + 0] = v.x; wd[g][q * 2 + 1] = v.y;
    }
  }
#pragma unroll
  for (int g = 0; g < 4; ++g)
#pragma unroll
    for (int q = 0; q < 30; ++q) PIN(wd[g][q]);

  __shared__ float2 dl2[240];      // 480 floats: staged hraw, wave-local regions
  __shared__ float  partbuf[1024]; // 8 waves x 32 j x 4 gates
  __shared__ float  b_s[128];
  __shared__ float  c_s[32];
  if (tid < 128) {
    const int ix = wg * 32 + (tid & 31);
    b_s[tid] = (ix < INP) ? btot[(tid >> 5) * INP + ix] : 0.0f;
  }
  if (tid < 32) c_s[tid] = 0.0f;

  for (int t = 0; t < SEQ; ++t) {
    if (t > 0) {
      // ---- poll-stage hraw_t: wave-local granules, tight loop ----
      const f32x2* gp = (const f32x2*)(hraw + (size_t)(t & 3) * 512) + gidx;
      f32x2 g2;
      for (;;) {
        g2 = mall8(gp);
        if ((g2.x == g2.x) & (g2.y == g2.y)) break;
      }
      if (l < 30) dl2[gidx] = make_float2(g2.x, g2.y);
      // no staging barrier: same-wave DS ordering suffices
    }

    float2 acc0 = make_float2(0, 0), acc1 = acc0, acc2 = acc0, acc3 = acc0;
    if (t == 0) {
      if (valid) {
#pragma unroll 4
        for (int q = 0; q < 32; ++q) {
          const float4 hv = *(const float4*)(henc + kc * 128 + 4 * q);
          const float4 w0 = *(const float4*)(dWih + (size_t)(0 * INP + idx) * EMB + kc * 128 + 4 * q);
          const float4 w1 = *(const float4*)(dWih + (size_t)(1 * INP + idx) * EMB + kc * 128 + 4 * q);
          const float4 w2 = *(const float4*)(dWih + (size_t)(2 * INP + idx) * EMB + kc * 128 + 4 * q);
          const float4 w3 = *(const float4*)(dWih + (size_t)(3 * INP + idx) * EMB + kc * 128 + 4 * q);
          acc0.x += w0.x * hv.x + w0.z * hv.z; acc0.y += w0.y * hv.y + w0.w * hv.w;
          acc1.x += w1.x * hv.x + w1.z * hv.z; acc1.y += w1.y * hv.y + w1.w * hv.w;
          acc2.x += w2.x * hv.x + w2.z * hv.z; acc2.y += w2.y * hv.y + w2.w * hv.w;
          acc3.x += w3.x * hv.x + w3.z * hv.z; acc3.y += w3.y * hv.y + w3.w * hv.w;
        }
      }
    } else {
#pragma unroll
      for (int q = 0; q < 15; ++q) {
        const float2 hv = dl2[kc * 15 + q];
        acc0.x += wd[0][q * 2] * hv.x; acc0.y += wd[0][q * 2 + 1] * hv.y;
        acc1.x += wd[1][q * 2] * hv.x; acc1.y += wd[1][q * 2 + 1] * hv.y;
        acc2.x += wd[2][q * 2] * hv.x; acc2.y += wd[2][q * 2 + 1] * hv.y;
        acc3.x += wd[3][q * 2] * hv.x; acc3.y += wd[3][q * 2 + 1] * hv.y;
      }
    }
    float r0 = acc0.x + acc0.y, r1 = acc1.x + acc1.y, r2 = acc2.x + acc2.y, r3 = acc3.x + acc3.y;
    r0 += __shfl_xor(r0, 32); r1 += __shfl_xor(r1, 32);
    r2 += __shfl_xor(r2, 32); r3 += __shfl_xor(r3, 32);
    if ((tid & 63) < 32)
      *(float4*)(partbuf + (tid >> 6) * 128 + (tid & 31) * 4) = make_float4(r0, r1, r2, r3);
    __syncthreads();   // the ONLY per-step barrier

    if (tid < 32) {
      const int ix = wg * 32 + tid;
      // re-arm slot (t+3)&3 (barrier proved all WGs finished step t-1 reads)
      if (ix < 480)
        __hip_atomic_store(hraw + (size_t)((t + 3) & 3) * 512 + ix, QNAN,
                           __ATOMIC_RELAXED, __HIP_MEMORY_SCOPE_AGENT);
      float s0 = 0.f, s1 = 0.f, s2 = 0.f, s3 = 0.f;
#pragma unroll
      for (int w = 0; w < 8; ++w) {
        const float4 pv = *(const float4*)(partbuf + w * 128 + tid * 4);
        s0 += pv.x; s1 += pv.y; s2 += pv.z; s3 += pv.w;
      }
      const float gi = s0 + b_s[tid], gf = s1 + b_s[32 + tid];
      const float gg = s2 + b_s[64 + tid], go = s3 + b_s[96 + tid];
      const float cN = sigf(gf) * c_s[tid] + sigf(gi) * tanhf(gg);
      c_s[tid] = cN;
      const float hrN = sigf(go) * tanhf(cN);
      // drain re-arm store, then publish, then fire-and-forget out.
      asm volatile("s_waitcnt vmcnt(0)" ::: "memory");
      if (ix < 480)
        __hip_atomic_store(hraw + (size_t)((t + 1) & 3) * 512 + ix, (ix < INP) ? hrN : 0.0f,
                           __ATOMIC_RELAXED, __HIP_MEMORY_SCOPE_AGENT);
      if (ix < INP) out[(size_t)(SEQ - 1 - t) * INP + ix] = cN;
    }
  }
}

// ---------------- row softmax in-place on d_out (4096 x 457) ----------------
__global__ __launch_bounds__(512) void softmax_kernel(float* __restrict__ out) {
  const int row = blockIdx.x;
  const int tid = threadIdx.x;
  __shared__ float red[512];
  float* rp = out + (size_t)row * INP;
  float v = (tid < INP) ? rp[tid] : -INFINITY;
  red[tid] = v;
  __syncthreads();
#pragma unroll
  for (int off = 256; off > 0; off >>= 1) {
    if (tid < off) red[tid] = fmaxf(red[tid], red[tid + off]);
    __syncthreads();
  }
  const float m = red[0];
  __syncthreads();
  const float e = (tid < INP) ? expf(v - m) : 0.0f;
  red[tid] = e;
  __syncthreads();
#pragma unroll
  for (int off = 256; off > 0; off >>= 1) {
    if (tid < off) red[tid] = red[tid] + red[tid + off];
    __syncthreads();
  }
  const float s = red[0];
  if (tid < INP) rp[tid] = e / s;
}

extern "C" void kernel_launch(void* const* d_in, const int* in_sizes, int n_in,
                              void* d_out, int out_size, void* d_ws, size_t ws_size,
                              hipStream_t stream) {
  const float* x    = (const float*)d_in[0];
  const float* eWih = (const float*)d_in[1];
  const float* eWhh = (const float*)d_in[2];
  const float* ebih = (const float*)d_in[3];
  const float* ebhh = (const float*)d_in[4];
  const float* dWih = (const float*)d_in[5];
  const float* dWhh = (const float*)d_in[6];
  const float* dbih = (const float*)d_in[7];
  const float* dbhh = (const float*)d_in[8];
  const float* dWhr = (const float*)d_in[9];
  float* out = (float*)d_out;
  char* ws = (char*)d_ws;

  // ws layout:
  // [0, 32768):        hbuf: depth-2 h ring (2 x 2048 f32; slots 2,3 unused). slot0
  //                    pre-zeroed = h_0; h_enc = h_4096 lands in slot0 (4096&1==0).
  // [32768, 40960):    hraw ring: 4 slots x 512 f32, NaN-init (dec; slot0 never polled).
  // [40960, 41984):    cnt[4]: enc publish counters (monotone; zeroed each launch)
  // [41984, 74752):    bsum (4*EMB f32)
  // [74752, 82944):    btot (4*INP f32, padded)
  // [82944, +3.51MB):  Wfold 1828x480
  float* hbuf  = (float*)(ws + 0);
  float* hraw  = (float*)(ws + 32768);
  unsigned* cnt = (unsigned*)(ws + 40960);
  float* bsum  = (float*)(ws + 41984);
  float* btot  = (float*)(ws + 74752);
  float* Wfold = (float*)(ws + 82944);

  hipMemsetAsync(ws, 0xFF, 40960, stream);        // hraw ring -> NaN sentinel (hbuf too; harmless)
  hipMemsetAsync(ws, 0x00, 8192, stream);         // hbuf slot0 -> h_0 = 0
  hipMemsetAsync(ws + 40960, 0x00, 1024, stream); // counters -> 0
  bias_kernel<<<40, 256, 0, stream>>>(ebih, ebhh, dbih, dbhh, bsum, btot);
  fold_gemm<<<dim3(8, 29), 256, 0, stream>>>(dWih, dWhh, dWhr, Wfold);
  enc_kernel<<<NWG_E, 512, 0, stream>>>(x, eWih, eWhh, bsum, hbuf, cnt);
  dec_kernel<<<NWG_D, 512, 0, stream>>>(dWih, Wfold, btot, hbuf, hraw, out);
  softmax_kernel<<<SEQ, 512, 0, stream>>>(out);
}

// Round 6
// 18648.930 us; speedup vs baseline: 2.8320x; 2.8320x over previous
//
#include <hip/hip_runtime.h>
#include <cmath>

#define SEQ 4096
#define INP 457
#define EMB 2048
#define NWG_E 256   // encoder: 1 WG (512 thr) per CU; 160 weight floats/thread pinned in VGPRs
#define NWG_D 16    // decoder: 16 WGs x 32 c-indices = 512 >= 457
#define NCPY 8      // h-ring replication factor (kills same-line poll contention)

typedef unsigned long long u64t;
typedef float f32x4 __attribute__((ext_vector_type(4)));
typedef float f32x2 __attribute__((ext_vector_type(2)));

__device__ __forceinline__ float sigf(float v) { return 1.0f / (1.0f + expf(-v)); }

// Opaque pin: value becomes output of an opaque asm -> compiler cannot rematerialize
// the original load; the value must stay live in a VGPR.
#define PIN(v) asm volatile("" : "+v"(v))

#define QNAN __builtin_bit_cast(float, 0x7fc00000u)

// MALL-coherent loads (device scope, bypass L1+L2). Manual vmcnt(0) because the compiler
// cannot see these are loads. Hidden asm vmem only makes compiler waitcnts over-wait -> safe.
__device__ __forceinline__ f32x4 mall16(const f32x4* p) {
  f32x4 v;
  asm volatile("global_load_dwordx4 %0, %1, off sc0 sc1\n\ts_waitcnt vmcnt(0)"
               : "=v"(v) : "v"(p) : "memory");
  return v;
}
__device__ __forceinline__ f32x2 mall8(const f32x2* p) {
  f32x2 v;
  asm volatile("global_load_dwordx2 %0, %1, off sc0 sc1\n\ts_waitcnt vmcnt(0)"
               : "=v"(v) : "v"(p) : "memory");
  return v;
}

// ---------------- bias precompute ----------------
__global__ void bias_kernel(const float* __restrict__ ebih, const float* __restrict__ ebhh,
                            const float* __restrict__ dbih, const float* __restrict__ dbhh,
                            float* __restrict__ bsum, float* __restrict__ btot) {
  int i = blockIdx.x * 256 + threadIdx.x;
  if (i < 4 * EMB) bsum[i] = ebih[i] + ebhh[i];
  if (i < 4 * INP) btot[i] = dbih[i] + dbhh[i];
}

// ---------------- Wfold = (dec_Wih + dec_Whh) @ dec_Whr  (1828 x 480, pad cols zero) ----------------
__global__ __launch_bounds__(256) void fold_gemm(const float* __restrict__ dWih,
                                                 const float* __restrict__ dWhh,
                                                 const float* __restrict__ dWhr,
                                                 float* __restrict__ C) {
  const int bx = blockIdx.x, by = blockIdx.y;
  const int tid = threadIdx.x;
  const int tx = tid & 15, ty = tid >> 4;
  __shared__ float As[16][65];
  __shared__ float Bs[16][65];
  float acc[4][4] = {};
  for (int k0 = 0; k0 < EMB; k0 += 16) {
#pragma unroll
    for (int e = 0; e < 4; ++e) {
      int eid = tid * 4 + e;
      int m = eid >> 4, k = eid & 15;
      int row = by * 64 + m;
      float v = 0.0f;
      if (row < 4 * INP) {
        size_t a = (size_t)row * EMB + k0 + k;
        v = dWih[a] + dWhh[a];
      }
      As[k][m] = v;
    }
#pragma unroll
    for (int e = 0; e < 4; ++e) {
      int eid = tid * 4 + e;
      int k = eid >> 6, c = eid & 63;
      int col = bx * 64 + c;
      Bs[k][c] = (col < INP) ? dWhr[(size_t)(k0 + k) * INP + col] : 0.0f;
    }
    __syncthreads();
#pragma unroll
    for (int k = 0; k < 16; ++k) {
      float a0 = As[k][ty * 4 + 0], a1 = As[k][ty * 4 + 1], a2 = As[k][ty * 4 + 2], a3 = As[k][ty * 4 + 3];
      float b0 = Bs[k][tx * 4 + 0], b1 = Bs[k][tx * 4 + 1], b2 = Bs[k][tx * 4 + 2], b3 = Bs[k][tx * 4 + 3];
      acc[0][0] += a0 * b0; acc[0][1] += a0 * b1; acc[0][2] += a0 * b2; acc[0][3] += a0 * b3;
      acc[1][0] += a1 * b0; acc[1][1] += a1 * b1; acc[1][2] += a1 * b2; acc[1][3] += a1 * b3;
      acc[2][0] += a2 * b0; acc[2][1] += a2 * b1; acc[2][2] += a2 * b2; acc[2][3] += a2 * b3;
      acc[3][0] += a3 * b0; acc[3][1] += a3 * b1; acc[3][2] += a3 * b2; acc[3][3] += a3 * b3;
    }
    __syncthreads();
  }
#pragma unroll
  for (int i = 0; i < 4; ++i) {
    int row = by * 64 + ty * 4 + i;
    if (row >= 4 * INP) continue;
#pragma unroll
    for (int j = 0; j < 4; ++j) {
      int col = bx * 64 + tx * 4 + j;
      if (col < 480) C[(size_t)row * 480 + col] = acc[i][j];
    }
  }
}

// ---------------- persistent encoder: R3 protocol + 8-way replicated h ring ----------------
// 256 WGs x 512 thr. WG w owns h-indices [w*8, w*8+8). Weights pinned in VGPRs (160 f/thread).
// Data-is-the-flag on a depth-4 ring of h vectors (NaN = empty), NOW x NCPY copies:
// hbuf[slot][copy][2048]. Consumer WG w polls ONLY copy (w&7) -> pollers per 64B line drop
// from ~1024 to ~128 (R5 evidence: hot-line serialization, not aggregate volume, sets poll
// latency). Producers re-arm + publish ALL 8 copies (8 lanes x 8 stores, pipelined, one
// vmcnt(0) drains all). Re-arm proof unchanged and copy-independent: my barrier at step t
// proves every producer published h(t) to MY copy, hence passed ITS step t-1 barrier, hence
// finished reading slot (t+3)&3 in ITS copy. Reset-drain before h(t+1) publish orders the
// NaN resets of ALL copies before any consumer can transitively reach step t+3. Airtight.
__global__ __launch_bounds__(512) __attribute__((amdgpu_waves_per_eu(2, 2))) void enc_kernel(
    const float* __restrict__ x, const float* __restrict__ Wih,
    const float* __restrict__ Whh, const float* __restrict__ bsum,
    float* __restrict__ hbuf) {
  const int tid = threadIdx.x;
  const int wg  = blockIdx.x;
  const int j   = tid & 7;
  const int kc  = tid >> 3;            // 0..63 (wave-local: wave w has kc in [8w, 8w+8))
  const int jbase = wg * 8;
  const int mycpy = wg & (NCPY - 1);

  float wh[4][32];
  float wi[4][8];
#pragma unroll
  for (int g = 0; g < 4; ++g) {
    const size_t row = (size_t)(g * EMB + jbase + j);
    const float* wp = Whh + row * EMB + kc * 32;
#pragma unroll
    for (int q = 0; q < 8; ++q) {
      const float4 v = *(const float4*)(wp + 4 * q);
      wh[g][q * 4 + 0] = v.x; wh[g][q * 4 + 1] = v.y;
      wh[g][q * 4 + 2] = v.z; wh[g][q * 4 + 3] = v.w;
    }
    const float* ip = Wih + row * INP;
#pragma unroll
    for (int i = 0; i < 8; ++i) {
      const int c = kc * 8 + i;
      wi[g][i] = (c < INP) ? ip[c] : 0.0f;
    }
  }
  // pin all 160 weight floats in VGPRs
#pragma unroll
  for (int g = 0; g < 4; ++g) {
#pragma unroll
    for (int q = 0; q < 32; ++q) PIN(wh[g][q]);
#pragma unroll
    for (int q = 0; q < 8; ++q) PIN(wi[g][q]);
  }

  __shared__ float4 hl4[512];          // 8 KB: h_t, swizzled 16B granules, wave-local regions
  __shared__ float4 xl4[128];          // 2 KB: x_t (512 floats, pad 0), wave-local regions
  __shared__ float  partbuf[256];      // 8 waves x 8 j x 4 gates
  __shared__ float  b_s[32];
  __shared__ float  c_s[8];
  if (tid < 32) b_s[tid] = bsum[(tid >> 3) * EMB + jbase + (tid & 7)];
  if (tid < 8)  c_s[tid] = 0.0f;
  const int sw = kc & 7;
  const int hphys = tid ^ ((tid >> 3) & 7);   // write-side granule swizzle (stays in wave region)
  const int xi = (tid < INP) ? tid : 0;

  for (int t = 0; t < SEQ; ++t) {
    // ---- x load (cached, issued before poll) ----
    const float xraw = x[(size_t)t * INP + xi];

    // ---- poll own 16B granule of h_t in MY copy (NaN = not yet written) ----
    const f32x4* gp = (const f32x4*)(hbuf + (size_t)((t & 3) * NCPY + mycpy) * EMB) + tid;
    f32x4 g4;
    for (;;) {
      g4 = mall16(gp);
      if ((g4.x == g4.x) & (g4.y == g4.y) & (g4.z == g4.z) & (g4.w == g4.w)) break;
    }
    hl4[hphys] = make_float4(g4.x, g4.y, g4.z, g4.w);
    ((float*)xl4)[tid] = (tid < INP) ? xraw : 0.0f;
    // no barrier: same-wave DS ordering suffices (wave reads only its own region)

    // ---- MAC: 4 gates x (8 x + 32 h) ----
    float4 a0 = make_float4(0, 0, 0, 0), a1 = a0, a2 = a0, a3 = a0;
#pragma unroll
    for (int q = 0; q < 2; ++q) {
      const float4 xq = xl4[kc * 2 + q];
      a0.x += wi[0][q * 4 + 0] * xq.x; a0.y += wi[0][q * 4 + 1] * xq.y; a0.z += wi[0][q * 4 + 2] * xq.z; a0.w += wi[0][q * 4 + 3] * xq.w;
      a1.x += wi[1][q * 4 + 0] * xq.x; a1.y += wi[1][q * 4 + 1] * xq.y; a1.z += wi[1][q * 4 + 2] * xq.z; a1.w += wi[1][q * 4 + 3] * xq.w;
      a2.x += wi[2][q * 4 + 0] * xq.x; a2.y += wi[2][q * 4 + 1] * xq.y; a2.z += wi[2][q * 4 + 2] * xq.z; a2.w += wi[2][q * 4 + 3] * xq.w;
      a3.x += wi[3][q * 4 + 0] * xq.x; a3.y += wi[3][q * 4 + 1] * xq.y; a3.z += wi[3][q * 4 + 2] * xq.z; a3.w += wi[3][q * 4 + 3] * xq.w;
    }
#pragma unroll
    for (int q = 0; q < 8; ++q) {
      const float4 hv = hl4[kc * 8 + (q ^ sw)];   // holds LOGICAL granule kc*8+q
      const int b = q * 4;
      a0.x += wh[0][b + 0] * hv.x; a0.y += wh[0][b + 1] * hv.y; a0.z += wh[0][b + 2] * hv.z; a0.w += wh[0][b + 3] * hv.w;
      a1.x += wh[1][b + 0] * hv.x; a1.y += wh[1][b + 1] * hv.y; a1.z += wh[1][b + 2] * hv.z; a1.w += wh[1][b + 3] * hv.w;
      a2.x += wh[2][b + 0] * hv.x; a2.y += wh[2][b + 1] * hv.y; a2.z += wh[2][b + 2] * hv.z; a2.w += wh[2][b + 3] * hv.w;
      a3.x += wh[3][b + 0] * hv.x; a3.y += wh[3][b + 1] * hv.y; a3.z += wh[3][b + 2] * hv.z; a3.w += wh[3][b + 3] * hv.w;
    }

    // ---- reduce 8 kc-chunks inside each wave (lane bits 3,4,5), partials to LDS ----
    float r0 = (a0.x + a0.y) + (a0.z + a0.w);
    float r1 = (a1.x + a1.y) + (a1.z + a1.w);
    float r2 = (a2.x + a2.y) + (a2.z + a2.w);
    float r3 = (a3.x + a3.y) + (a3.z + a3.w);
#pragma unroll
    for (int m = 8; m < 64; m <<= 1) {
      r0 += __shfl_xor(r0, m); r1 += __shfl_xor(r1, m);
      r2 += __shfl_xor(r2, m); r3 += __shfl_xor(r3, m);
    }
    if ((tid & 63) < 8)
      *(float4*)(partbuf + (tid >> 6) * 32 + j * 4) = make_float4(r0, r1, r2, r3);
    __syncthreads();   // the ONLY per-step barrier

    // ---- wave0: re-arm ring (all copies), gather, activate, publish (all copies) ----
    if (tid < 8) {
      float* const rearm = hbuf + (size_t)(((t + 3) & 3) * NCPY) * EMB + jbase + tid;
#pragma unroll
      for (int c = 0; c < NCPY; ++c)
        __hip_atomic_store(rearm + (size_t)c * EMB, QNAN,
                           __ATOMIC_RELAXED, __HIP_MEMORY_SCOPE_AGENT);
      float s0 = 0.f, s1 = 0.f, s2 = 0.f, s3 = 0.f;
#pragma unroll
      for (int w = 0; w < 8; ++w) {
        const float4 pv = *(const float4*)(partbuf + w * 32 + tid * 4);
        s0 += pv.x; s1 += pv.y; s2 += pv.z; s3 += pv.w;
      }
      const float gi = s0 + b_s[tid], gf = s1 + b_s[8 + tid];
      const float gg = s2 + b_s[16 + tid], go = s3 + b_s[24 + tid];
      const float cN = sigf(gf) * c_s[tid] + sigf(gi) * tanhf(gg);
      c_s[tid] = cN;
      const float hN = sigf(go) * tanhf(cN);
      // drain the re-arm stores (all copies) so NaN resets are visible BEFORE h_{t+1}
      asm volatile("s_waitcnt vmcnt(0)" ::: "memory");
      float* const pub = hbuf + (size_t)(((t + 1) & 3) * NCPY) * EMB + jbase + tid;
#pragma unroll
      for (int c = 0; c < NCPY; ++c)
        __hip_atomic_store(pub + (size_t)c * EMB, hN,
                           __ATOMIC_RELAXED, __HIP_MEMORY_SCOPE_AGENT);
    }
  }
}

// ---------------- persistent decoder (exact R3-proven version) ----------------
// 16 WGs x 512 thr. WG w owns c-indices [w*32, w*32+32). Wfold 4x30 = 120 floats/thread pinned.
// Data-is-the-flag on a depth-4 hraw ring (NaN = empty), MALL-scope (sc0 sc1) polls.
// Wave v's MAC reads dl2 granules [30v, 30v+30); lanes l<30 poll+stage those, lanes >=30 poll
// a duplicate granule folded into [0,30) of the SAME wave region. Pad lanes 457..479 are
// stored 0.0f every step so all polled granules terminate.
__global__ __launch_bounds__(512) __attribute__((amdgpu_waves_per_eu(2, 2))) void dec_kernel(
    const float* __restrict__ dWih, const float* __restrict__ Wfold,
    const float* __restrict__ btot, const float* __restrict__ henc,
    float* __restrict__ hraw, float* __restrict__ out) {
  const int tid = threadIdx.x;
  const int wg  = blockIdx.x;
  const int j   = tid & 31;
  const int kc  = tid >> 5;          // 0..15 (wave-local: wave v has kc in {2v, 2v+1})
  const int idx = wg * 32 + j;
  const bool valid = (idx < INP);
  const int id0 = valid ? idx : 0;
  const int l   = tid & 63;
  const int wv  = tid >> 6;
  int gl = l;                         // fold lane into [0,30): l, l-30, l-60
  if (gl >= 30) gl -= 30;
  if (gl >= 30) gl -= 30;
  const int gidx = 30 * wv + gl;      // polled u64 granule, always in-range & wave-local

  float wd[4][30];
#pragma unroll
  for (int g = 0; g < 4; ++g) {
    const float* wp = Wfold + (size_t)(g * INP + id0) * 480 + kc * 30;
#pragma unroll
    for (int q = 0; q < 15; ++q) {
      const float2 v = valid ? *(const float2*)(wp + 2 * q) : make_float2(0.0f, 0.0f);
      wd[g][q * 2 + 0] = v.x; wd[g][q * 2 + 1] = v.y;
    }
  }
#pragma unroll
  for (int g = 0; g < 4; ++g)
#pragma unroll
    for (int q = 0; q < 30; ++q) PIN(wd[g][q]);

  __shared__ float2 dl2[240];      // 480 floats: staged hraw, wave-local regions
  __shared__ float  partbuf[1024]; // 8 waves x 32 j x 4 gates
  __shared__ float  b_s[128];
  __shared__ float  c_s[32];
  if (tid < 128) {
    const int ix = wg * 32 + (tid & 31);
    b_s[tid] = (ix < INP) ? btot[(tid >> 5) * INP + ix] : 0.0f;
  }
  if (tid < 32) c_s[tid] = 0.0f;

  for (int t = 0; t < SEQ; ++t) {
    if (t > 0) {
      // ---- poll-stage hraw_t: wave-local granules, tight loop ----
      const f32x2* gp = (const f32x2*)(hraw + (size_t)(t & 3) * 512) + gidx;
      f32x2 g2;
      for (;;) {
        g2 = mall8(gp);
        if ((g2.x == g2.x) & (g2.y == g2.y)) break;
      }
      if (l < 30) dl2[gidx] = make_float2(g2.x, g2.y);
      // no staging barrier: same-wave DS ordering suffices
    }

    float2 acc0 = make_float2(0, 0), acc1 = acc0, acc2 = acc0, acc3 = acc0;
    if (t == 0) {
      if (valid) {
#pragma unroll 4
        for (int q = 0; q < 32; ++q) {
          const float4 hv = *(const float4*)(henc + kc * 128 + 4 * q);
          const float4 w0 = *(const float4*)(dWih + (size_t)(0 * INP + idx) * EMB + kc * 128 + 4 * q);
          const float4 w1 = *(const float4*)(dWih + (size_t)(1 * INP + idx) * EMB + kc * 128 + 4 * q);
          const float4 w2 = *(const float4*)(dWih + (size_t)(2 * INP + idx) * EMB + kc * 128 + 4 * q);
          const float4 w3 = *(const float4*)(dWih + (size_t)(3 * INP + idx) * EMB + kc * 128 + 4 * q);
          acc0.x += w0.x * hv.x + w0.z * hv.z; acc0.y += w0.y * hv.y + w0.w * hv.w;
          acc1.x += w1.x * hv.x + w1.z * hv.z; acc1.y += w1.y * hv.y + w1.w * hv.w;
          acc2.x += w2.x * hv.x + w2.z * hv.z; acc2.y += w2.y * hv.y + w2.w * hv.w;
          acc3.x += w3.x * hv.x + w3.z * hv.z; acc3.y += w3.y * hv.y + w3.w * hv.w;
        }
      }
    } else {
#pragma unroll
      for (int q = 0; q < 15; ++q) {
        const float2 hv = dl2[kc * 15 + q];
        acc0.x += wd[0][q * 2] * hv.x; acc0.y += wd[0][q * 2 + 1] * hv.y;
        acc1.x += wd[1][q * 2] * hv.x; acc1.y += wd[1][q * 2 + 1] * hv.y;
        acc2.x += wd[2][q * 2] * hv.x; acc2.y += wd[2][q * 2 + 1] * hv.y;
        acc3.x += wd[3][q * 2] * hv.x; acc3.y += wd[3][q * 2 + 1] * hv.y;
      }
    }
    float r0 = acc0.x + acc0.y, r1 = acc1.x + acc1.y, r2 = acc2.x + acc2.y, r3 = acc3.x + acc3.y;
    r0 += __shfl_xor(r0, 32); r1 += __shfl_xor(r1, 32);
    r2 += __shfl_xor(r2, 32); r3 += __shfl_xor(r3, 32);
    if ((tid & 63) < 32)
      *(float4*)(partbuf + (tid >> 6) * 128 + (tid & 31) * 4) = make_float4(r0, r1, r2, r3);
    __syncthreads();   // the ONLY per-step barrier

    if (tid < 32) {
      const int ix = wg * 32 + tid;
      // re-arm slot (t+3)&3 (barrier proved all WGs finished step t-1 reads)
      if (ix < 480)
        __hip_atomic_store(hraw + (size_t)((t + 3) & 3) * 512 + ix, QNAN,
                           __ATOMIC_RELAXED, __HIP_MEMORY_SCOPE_AGENT);
      float s0 = 0.f, s1 = 0.f, s2 = 0.f, s3 = 0.f;
#pragma unroll
      for (int w = 0; w < 8; ++w) {
        const float4 pv = *(const float4*)(partbuf + w * 128 + tid * 4);
        s0 += pv.x; s1 += pv.y; s2 += pv.z; s3 += pv.w;
      }
      const float gi = s0 + b_s[tid], gf = s1 + b_s[32 + tid];
      const float gg = s2 + b_s[64 + tid], go = s3 + b_s[96 + tid];
      const float cN = sigf(gf) * c_s[tid] + sigf(gi) * tanhf(gg);
      c_s[tid] = cN;
      const float hrN = sigf(go) * tanhf(cN);
      // drain re-arm store, then publish, then fire-and-forget out.
      asm volatile("s_waitcnt vmcnt(0)" ::: "memory");
      if (ix < 480)
        __hip_atomic_store(hraw + (size_t)((t + 1) & 3) * 512 + ix, (ix < INP) ? hrN : 0.0f,
                           __ATOMIC_RELAXED, __HIP_MEMORY_SCOPE_AGENT);
      if (ix < INP) out[(size_t)(SEQ - 1 - t) * INP + ix] = cN;
    }
  }
}

// ---------------- row softmax in-place on d_out (4096 x 457) ----------------
__global__ __launch_bounds__(512) void softmax_kernel(float* __restrict__ out) {
  const int row = blockIdx.x;
  const int tid = threadIdx.x;
  __shared__ float red[512];
  float* rp = out + (size_t)row * INP;
  float v = (tid < INP) ? rp[tid] : -INFINITY;
  red[tid] = v;
  __syncthreads();
#pragma unroll
  for (int off = 256; off > 0; off >>= 1) {
    if (tid < off) red[tid] = fmaxf(red[tid], red[tid + off]);
    __syncthreads();
  }
  const float m = red[0];
  __syncthreads();
  const float e = (tid < INP) ? expf(v - m) : 0.0f;
  red[tid] = e;
  __syncthreads();
#pragma unroll
  for (int off = 256; off > 0; off >>= 1) {
    if (tid < off) red[tid] = red[tid] + red[tid + off];
    __syncthreads();
  }
  const float s = red[0];
  if (tid < INP) rp[tid] = e / s;
}

extern "C" void kernel_launch(void* const* d_in, const int* in_sizes, int n_in,
                              void* d_out, int out_size, void* d_ws, size_t ws_size,
                              hipStream_t stream) {
  const float* x    = (const float*)d_in[0];
  const float* eWih = (const float*)d_in[1];
  const float* eWhh = (const float*)d_in[2];
  const float* ebih = (const float*)d_in[3];
  const float* ebhh = (const float*)d_in[4];
  const float* dWih = (const float*)d_in[5];
  const float* dWhh = (const float*)d_in[6];
  const float* dbih = (const float*)d_in[7];
  const float* dbhh = (const float*)d_in[8];
  const float* dWhr = (const float*)d_in[9];
  float* out = (float*)d_out;
  char* ws = (char*)d_ws;

  // ws layout:
  // [0, 262144):         hbuf ring: 4 slots x NCPY(8) copies x 2048 f32. Slot0 (all copies)
  //                      pre-zeroed = h_0; rest NaN. h_enc = h_4096 lands in slot0 (4096&3==0),
  //                      copy0 = first 8KB -> dec reads it as henc directly.
  // [262144, 270336):    hraw ring: 4 slots x 512 f32, NaN-init (dec; slot0 never polled).
  // [270336, 303104):    bsum (4*EMB f32)
  // [303104, 311296):    btot (4*INP f32, padded)
  // [311296, +3.51MB):   Wfold 1828x480
  float* hbuf  = (float*)(ws + 0);
  float* hraw  = (float*)(ws + 262144);
  float* bsum  = (float*)(ws + 270336);
  float* btot  = (float*)(ws + 303104);
  float* Wfold = (float*)(ws + 311296);

  hipMemsetAsync(ws, 0xFF, 270336, stream);   // hbuf (all slots/copies) + hraw -> NaN sentinel
  hipMemsetAsync(ws, 0x00, 65536, stream);    // hbuf slot0, all 8 copies -> h_0 = 0
  bias_kernel<<<40, 256, 0, stream>>>(ebih, ebhh, dbih, dbhh, bsum, btot);
  fold_gemm<<<dim3(8, 29), 256, 0, stream>>>(dWih, dWhh, dWhr, Wfold);
  enc_kernel<<<NWG_E, 512, 0, stream>>>(x, eWih, eWhh, bsum, hbuf);
  dec_kernel<<<NWG_D, 512, 0, stream>>>(dWih, Wfold, btot, hbuf, hraw, out);
  softmax_kernel<<<SEQ, 512, 0, stream>>>(out);
}